// Round 2
// baseline (135.058 us; speedup 1.0000x reference)
//
#include <hip/hip_runtime.h>
#include <math.h>

#define HU 2048
#define H3 6144

__device__ __forceinline__ float dot4(float4 a, float4 b){
  return a.x*b.x + a.y*b.y + a.z*b.z + a.w*b.w;
}
__device__ __forceinline__ float wred(float v){
  #pragma unroll
  for (int off = 32; off > 0; off >>= 1) v += __shfl_down(v, off, 64);
  return v;
}
__device__ __forceinline__ float sigm(float x){ return 1.0f/(1.0f + __expf(-x)); }

// ---------------- encoder: x = relu(obs @ W_enc.T + b_enc) ----------------
__global__ void k_enc(const float* __restrict__ obs, const float* __restrict__ W,
                      const float* __restrict__ b, float* __restrict__ x){
  __shared__ float so[128];
  int tid = threadIdx.x;
  if (tid < 126) so[tid] = obs[tid];
  __syncthreads();
  int r = blockIdx.x * blockDim.x + tid;
  if (r < HU){
    const float* wr = W + r*42;
    float a0=0.f, a1=0.f, a2=0.f;
    #pragma unroll
    for (int k2 = 0; k2 < 42; ++k2){
      float w = wr[k2];
      a0 += w*so[k2]; a1 += w*so[42+k2]; a2 += w*so[84+k2];
    }
    float bb = b[r];
    x[r]        = fmaxf(a0+bb, 0.f);
    x[HU + r]   = fmaxf(a1+bb, 0.f);
    x[2*HU + r] = fmaxf(a2+bb, 0.f);
  }
}

// -------- dual-segment GEMV, K=2048, 3 batch vectors, bias added ----------
// blocks [0,1536): W0 rows 0..6143 with X0 -> O0[b*6144+row]
// blocks [1536,3072): W1 with X1 -> O1
__global__ __launch_bounds__(256) void k_gemv2k(
    const float* __restrict__ W0, const float* __restrict__ X0,
    const float* __restrict__ b0, float* __restrict__ O0,
    const float* __restrict__ W1, const float* __restrict__ X1,
    const float* __restrict__ b1, float* __restrict__ O1){
  __shared__ float4 shX[1536];
  int blk = blockIdx.x;
  int seg = (blk >= 1536);
  const float* W    = seg ? W1 : W0;
  const float* X    = seg ? X1 : X0;
  const float* bias = seg ? b1 : b0;
  float* O          = seg ? O1 : O0;
  int tid = threadIdx.x;
  const float4* X4 = (const float4*)X;
  #pragma unroll
  for (int i = 0; i < 6; ++i) shX[tid + i*256] = X4[tid + i*256];
  __syncthreads();
  int wave = tid >> 6, lane = tid & 63;
  int row = (seg ? blk - 1536 : blk) * 4 + wave;
  const float4* Wr = (const float4*)(W + (size_t)row * 2048);
  float a0=0.f, a1=0.f, a2=0.f;
  #pragma unroll
  for (int it = 0; it < 8; ++it){
    int c = it*64 + lane;
    float4 w = Wr[c];
    a0 += dot4(w, shX[c]);
    a1 += dot4(w, shX[512 + c]);
    a2 += dot4(w, shX[1024 + c]);
  }
  a0 = wred(a0); a1 = wred(a1); a2 = wred(a2);
  if (lane == 0){
    float bb = bias[row];
    O[row] = a0 + bb; O[H3 + row] = a1 + bb; O[2*H3 + row] = a2 + bb;
  }
}

// GRU gate combine for the comm cell (h = hidden_state)
__global__ void k_gate_c(const float* __restrict__ gi, const float* __restrict__ gh,
                         const float* __restrict__ hprev,
                         float* __restrict__ hout_ws, float* __restrict__ dout){
  int id = blockIdx.x * blockDim.x + threadIdx.x;
  if (id >= 3*HU) return;
  int b = id >> 11, u = id & 2047;
  const float* gib = gi + b*H3;
  const float* ghb = gh + b*H3;
  float r = sigm(gib[u]      + ghb[u]);
  float z = sigm(gib[HU+u]   + ghb[HU+u]);
  float n = tanhf(gib[2*HU+u] + r*ghb[2*HU+u]);
  float h = hprev[id];
  float o = (1.f - z)*n + z*h;
  hout_ws[id] = o;
  dout[id] = o;
}

// --- big pass: stream Wih_f, Wih_r ONCE producing gi for BOTH steps; + q,k ---
// blocks [0,1536): Wih_f ; [1536,3072): Wih_r ; [3072,3200): Wq ; [3200,3328): Wk
// gi layout: [(t*3+b)*6144 + row]
__global__ __launch_bounds__(256) void k_ih(
    const float* __restrict__ Wf, const float* __restrict__ bf, float* __restrict__ giF,
    const float* __restrict__ Wr_, const float* __restrict__ br, float* __restrict__ giR,
    const float* __restrict__ Wq, float* __restrict__ q,
    const float* __restrict__ Wk, float* __restrict__ kk,
    const float* __restrict__ hout){
  __shared__ float4 shH[1536];
  int tid = threadIdx.x;
  const float4* H4 = (const float4*)hout;
  #pragma unroll
  for (int i = 0; i < 6; ++i) shH[tid + i*256] = H4[tid + i*256];
  __syncthreads();
  int blk = blockIdx.x;
  int wave = tid >> 6, lane = tid & 63;
  if (blk < 3072){
    int segr = (blk >= 1536);
    const float* W    = segr ? Wr_ : Wf;
    const float* bias = segr ? br  : bf;
    float* gi         = segr ? giR : giF;
    int row = (segr ? blk - 1536 : blk) * 4 + wave;
    const float4* Wrow = (const float4*)(W + (size_t)row * 4096);
    float s0=0.f,s1=0.f,s2=0.f,n0=0.f,n1=0.f,n2=0.f;
    #pragma unroll
    for (int it = 0; it < 8; ++it){          // first half: self part
      int c = it*64 + lane;
      float4 w = Wrow[c];
      s0 += dot4(w, shH[c]); s1 += dot4(w, shH[512+c]); s2 += dot4(w, shH[1024+c]);
    }
    #pragma unroll
    for (int it = 0; it < 8; ++it){          // second half: neighbor part
      int c = it*64 + lane;
      float4 w = Wrow[512 + c];
      n0 += dot4(w, shH[c]); n1 += dot4(w, shH[512+c]); n2 += dot4(w, shH[1024+c]);
    }
    s0=wred(s0); s1=wred(s1); s2=wred(s2);
    n0=wred(n0); n1=wred(n1); n2=wred(n2);
    if (lane == 0){
      float bb = bias[row];
      // IDX = [[1,2],[0,2],[0,1]]
      gi[0*H3 + row] = s0 + n1 + bb;  // t=0 b=0 (nbr 1)
      gi[1*H3 + row] = s1 + n0 + bb;  // t=0 b=1 (nbr 0)
      gi[2*H3 + row] = s2 + n0 + bb;  // t=0 b=2 (nbr 0)
      gi[3*H3 + row] = s0 + n2 + bb;  // t=1 b=0 (nbr 2)
      gi[4*H3 + row] = s1 + n2 + bb;  // t=1 b=1 (nbr 2)
      gi[5*H3 + row] = s2 + n1 + bb;  // t=1 b=2 (nbr 1)
    }
  } else {
    int segk = (blk >= 3200);
    const float* W = segk ? Wk : Wq;
    float* O       = segk ? kk : q;
    int row = (segk ? blk - 3200 : blk - 3072) * 4 + wave; // 0..511
    const float4* Wrow = (const float4*)(W + (size_t)row * 2048);
    float a0=0.f, a1=0.f, a2=0.f;
    #pragma unroll
    for (int it = 0; it < 8; ++it){
      int c = it*64 + lane;
      float4 w = Wrow[c];
      a0 += dot4(w, shH[c]); a1 += dot4(w, shH[512+c]); a2 += dot4(w, shH[1024+c]);
    }
    a0=wred(a0); a1=wred(a1); a2=wred(a2);
    if (lane == 0){ O[row] = a0; O[512 + row] = a1; O[1024 + row] = a2; }
  }
}

// step 0 of both scans: h=0 so gh == bhh
// forward consumes seq[0]  -> giF t=0 block (b*H3)
// reverse consumes seq[1]  -> giR t=1 block ((3+b)*H3)   [seq reversed!]
__global__ void k_gate0(const float* __restrict__ giF, const float* __restrict__ bhf,
                        float* __restrict__ hf1,
                        const float* __restrict__ giR, const float* __restrict__ bhr,
                        float* __restrict__ hr1){
  int id = blockIdx.x * blockDim.x + threadIdx.x;
  if (id >= 3*HU) return;
  int b = id >> 11, u = id & 2047;
  {
    const float* gib = giF + b*H3;                    // forward t=0 block
    float r = sigm(gib[u]      + bhf[u]);
    float z = sigm(gib[HU+u]   + bhf[HU+u]);
    float n = tanhf(gib[2*HU+u] + r*bhf[2*HU+u]);
    hf1[id] = (1.f - z)*n;
  }
  {
    const float* gib = giR + (3 + b)*H3;              // reverse t=1 block
    float r = sigm(gib[u]      + bhr[u]);
    float z = sigm(gib[HU+u]   + bhr[HU+u]);
    float n = tanhf(gib[2*HU+u] + r*bhr[2*HU+u]);
    hr1[id] = (1.f - z)*n;
  }
}

// step 1 of both scans
// forward consumes seq[1] -> giF t=1 block; reverse consumes seq[0] -> giR t=0 block
__global__ void k_gate1(const float* __restrict__ giF, const float* __restrict__ ghF,
                        const float* __restrict__ hf1, float* __restrict__ hf2,
                        const float* __restrict__ giR, const float* __restrict__ ghR,
                        const float* __restrict__ hr1, float* __restrict__ hr2){
  int id = blockIdx.x * blockDim.x + threadIdx.x;
  if (id >= 3*HU) return;
  int b = id >> 11, u = id & 2047;
  {
    const float* gib = giF + (3 + b)*H3;              // forward t=1 block
    const float* ghb = ghF + b*H3;
    float r = sigm(gib[u]      + ghb[u]);
    float z = sigm(gib[HU+u]   + ghb[HU+u]);
    float n = tanhf(gib[2*HU+u] + r*ghb[2*HU+u]);
    hf2[id] = (1.f - z)*n + z*hf1[id];
  }
  {
    const float* gib = giR + b*H3;                    // reverse t=0 block
    const float* ghb = ghR + b*H3;
    float r = sigm(gib[u]      + ghb[u]);
    float z = sigm(gib[HU+u]   + ghb[HU+u]);
    float n = tanhf(gib[2*HU+u] + r*ghb[2*HU+u]);
    hr2[id] = (1.f - z)*n + z*hr1[id];
  }
}

// final small kernel: logits, gumbel softmax, q.k attention, xx, flag
__global__ __launch_bounds__(256) void k_final(
    const float* __restrict__ hf1, const float* __restrict__ hf2,
    const float* __restrict__ hr1, const float* __restrict__ hr2,
    const float* __restrict__ q, const float* __restrict__ kk,
    const float* __restrict__ Whard, const float* __restrict__ bhard,
    const float* __restrict__ gumbel, const float* __restrict__ obs,
    float* __restrict__ dout){
  __shared__ float slog[12];
  __shared__ float ssc[6];
  int tid = threadIdx.x;
  int wave = tid >> 6, lane = tid & 63;
  // 12 logit dots: d = row*2 + c ; row = i*2 + t ; h_hard row = [F | R]
  // h_hard[t=0] = [hf1 | outs_r[1]=hr2] ; h_hard[t=1] = [hf2 | outs_r[0]=hr1]
  #pragma unroll
  for (int s = 0; s < 3; ++s){
    int d = wave*3 + s;
    int rowi = d >> 1, c = d & 1;
    int i = rowi >> 1, t = rowi & 1;
    const float* F = (t ? hf2 : hf1) + i*HU;
    const float* R = (t ? hr1 : hr2) + i*HU;
    const float* w0 = Whard + c*4096;
    float acc = 0.f;
    for (int j = lane; j < HU; j += 64) acc += w0[j]*F[j] + w0[HU + j]*R[j];
    acc = wred(acc);
    if (lane == 0) slog[d] = acc + bhard[c];
  }
  // 6 attention score dots
  {
    const int nbr[6] = {1,2, 0,2, 0,1};   // IDX flattened, index = i*2+j
    for (int d = wave; d < 6; d += 4){
      int i = d >> 1;
      const float* qv = q + i*512;
      const float* kv = kk + nbr[d]*512;
      float acc = 0.f;
      for (int a = lane; a < 512; a += 64) acc += qv[a]*kv[a];
      acc = wred(acc);
      if (lane == 0) ssc[d] = acc * 0.04419417382415922f;  // 1/sqrt(512)
    }
  }
  __syncthreads();
  if (tid == 0){
    float y1[6];
    #pragma unroll
    for (int rr = 0; rr < 6; ++rr){
      float a0 = (slog[rr*2+0] + gumbel[rr*2+0]) * 100.0f;  // /TAU
      float a1 = (slog[rr*2+1] + gumbel[rr*2+1]) * 100.0f;
      y1[rr] = 1.0f/(1.0f + expf(a0 - a1));
    }
    #pragma unroll
    for (int i = 0; i < 3; ++i){
      float s0 = ssc[i*2], s1 = ssc[i*2+1];
      float m = fmaxf(s0, s1);
      float e0 = expf(s0 - m), e1 = expf(s1 - m);
      float inv = 1.0f/(e0 + e1);
      dout[6144 + i*2 + 0] = e0*inv * y1[i*2 + 0];
      dout[6144 + i*2 + 1] = e1*inv * y1[i*2 + 1];
    }
    // flag from obs
    const int idx[3][2] = {{1,2},{0,2},{0,1}};
    int temp[3][2];
    #pragma unroll
    for (int i = 0; i < 3; ++i){
      float res[2];
      #pragma unroll
      for (int j = 0; j < 2; ++j){
        float s = 0.f;
        for (int k2 = 0; k2 < 42; ++k2){
          float d2 = obs[i*42 + k2] - obs[idx[i][j]*42 + k2];
          s += d2*d2;
        }
        res[j] = s;
      }
      int jloc = (res[1] > res[0]) ? 1 : 0;   // argmax, first-on-tie
      float maxv = res[jloc];
      int jadj = (maxv != 0.0f && jloc >= i) ? jloc + 1 : jloc;
      int lo = min(i, jadj), hi = max(i, jadj);
      temp[i][0] = lo; temp[i][1] = hi;
    }
    bool eq01 = temp[0][0]==temp[1][0] && temp[0][1]==temp[1][1];
    bool eq02 = temp[0][0]==temp[2][0] && temp[0][1]==temp[2][1];
    bool eq12 = temp[1][0]==temp[2][0] && temp[1][1]==temp[2][1];
    int f0, f1;
    if (eq12){ f0 = temp[1][0]; f1 = temp[1][1]; }
    else if (eq01 || eq02){ f0 = temp[0][0]; f1 = temp[0][1]; }
    else { f0 = -1; f1 = -1; }
    dout[6150] = (float)f0;
    dout[6151] = (float)f1;
  }
}

extern "C" void kernel_launch(void* const* d_in, const int* in_sizes, int n_in,
                              void* d_out, int out_size, void* d_ws, size_t ws_size,
                              hipStream_t stream) {
  const float* obs    = (const float*)d_in[0];
  const float* hidden = (const float*)d_in[1];
  const float* gumbel = (const float*)d_in[2];
  const float* W_enc  = (const float*)d_in[3];
  const float* b_enc  = (const float*)d_in[4];
  const float* Wih_c  = (const float*)d_in[5];
  const float* Whh_c  = (const float*)d_in[6];
  const float* bih_c  = (const float*)d_in[7];
  const float* bhh_c  = (const float*)d_in[8];
  const float* Wih_f  = (const float*)d_in[9];
  const float* Whh_f  = (const float*)d_in[10];
  const float* bih_f  = (const float*)d_in[11];
  const float* bhh_f  = (const float*)d_in[12];
  const float* Wih_r  = (const float*)d_in[13];
  const float* Whh_r  = (const float*)d_in[14];
  const float* bih_r  = (const float*)d_in[15];
  const float* bhh_r  = (const float*)d_in[16];
  const float* W_hard = (const float*)d_in[17];
  const float* b_hard = (const float*)d_in[18];
  const float* Wq     = (const float*)d_in[19];
  const float* Wk     = (const float*)d_in[20];

  float* out = (float*)d_out;
  float* ws  = (float*)d_ws;
  float* x    = ws;            // 6144
  float* hout = ws + 6144;     // 6144
  float* gic  = ws + 12288;    // 18432
  float* ghc  = ws + 30720;    // 18432
  float* gif  = ws + 49152;    // 36864  [(t*3+b)*6144 + r]
  float* gir  = ws + 86016;    // 36864
  float* ghf  = ws + 122880;   // 18432
  float* ghr  = ws + 141312;   // 18432
  float* hf1  = ws + 159744;   // 6144
  float* hr1  = ws + 165888;   // 6144
  float* hf2  = ws + 172032;   // 6144
  float* hr2  = ws + 178176;   // 6144
  float* q    = ws + 184320;   // 1536
  float* kk   = ws + 185856;   // 1536

  k_enc<<<8, 256, 0, stream>>>(obs, W_enc, b_enc, x);
  k_gemv2k<<<3072, 256, 0, stream>>>(Wih_c, x, bih_c, gic, Whh_c, hidden, bhh_c, ghc);
  k_gate_c<<<24, 256, 0, stream>>>(gic, ghc, hidden, hout, out);
  k_ih<<<3328, 256, 0, stream>>>(Wih_f, bih_f, gif, Wih_r, bih_r, gir, Wq, q, Wk, kk, hout);
  k_gate0<<<24, 256, 0, stream>>>(gif, bhh_f, hf1, gir, bhh_r, hr1);
  k_gemv2k<<<3072, 256, 0, stream>>>(Whh_f, hf1, bhh_f, ghf, Whh_r, hr1, bhh_r, ghr);
  k_gate1<<<24, 256, 0, stream>>>(gif, ghf, hf1, hf2, gir, ghr, hr1, hr2);
  k_final<<<1, 256, 0, stream>>>(hf1, hf2, hr1, hr2, q, kk, W_hard, b_hard, gumbel, obs, out);
}

// Round 3
// 131.760 us; speedup vs baseline: 1.0250x; 1.0250x over previous
//
#include <hip/hip_runtime.h>
#include <math.h>

#define HU 2048
#define H3 6144

__device__ __forceinline__ float dot4(float4 a, float4 b){
  return a.x*b.x + a.y*b.y + a.z*b.z + a.w*b.w;
}
__device__ __forceinline__ float wred(float v){
  #pragma unroll
  for (int off = 32; off > 0; off >>= 1) v += __shfl_down(v, off, 64);
  return v;
}
__device__ __forceinline__ float sigm(float x){ return 1.0f/(1.0f + __expf(-x)); }

// ---------------- encoder: x = relu(obs @ W_enc.T + b_enc) ----------------
__global__ void k_enc(const float* __restrict__ obs, const float* __restrict__ W,
                      const float* __restrict__ b, float* __restrict__ x){
  __shared__ float so[128];
  int tid = threadIdx.x;
  if (tid < 126) so[tid] = obs[tid];
  __syncthreads();
  int r = blockIdx.x * blockDim.x + tid;
  if (r < HU){
    const float* wr = W + r*42;
    float a0=0.f, a1=0.f, a2=0.f;
    #pragma unroll
    for (int k2 = 0; k2 < 42; ++k2){
      float w = wr[k2];
      a0 += w*so[k2]; a1 += w*so[42+k2]; a2 += w*so[84+k2];
    }
    float bb = b[r];
    x[r]        = fmaxf(a0+bb, 0.f);
    x[HU + r]   = fmaxf(a1+bb, 0.f);
    x[2*HU + r] = fmaxf(a2+bb, 0.f);
  }
}

// -------- dual-segment GEMV, K=2048, 3 batch vectors, bias added ----------
// 512 threads = 8 waves = 8 rows per block.
// blocks [0,768): W0 rows with X0 -> O0[b*6144+row]
// blocks [768,1536): W1 with X1 -> O1
__global__ __launch_bounds__(512) void k_gemv2k(
    const float* __restrict__ W0, const float* __restrict__ X0,
    const float* __restrict__ b0, float* __restrict__ O0,
    const float* __restrict__ W1, const float* __restrict__ X1,
    const float* __restrict__ b1, float* __restrict__ O1){
  __shared__ float4 shX[1536];
  int blk = blockIdx.x;
  int seg = (blk >= 768);
  const float* W    = seg ? W1 : W0;
  const float* X    = seg ? X1 : X0;
  const float* bias = seg ? b1 : b0;
  float* O          = seg ? O1 : O0;
  int tid = threadIdx.x;
  const float4* X4 = (const float4*)X;
  #pragma unroll
  for (int i = 0; i < 3; ++i) shX[tid + i*512] = X4[tid + i*512];
  __syncthreads();
  int wave = tid >> 6, lane = tid & 63;
  int row = (seg ? blk - 768 : blk) * 8 + wave;
  const float4* Wr = (const float4*)(W + (size_t)row * 2048);
  // batch all 8 weight loads first (8KB/wave in flight), then compute
  float4 wv[8];
  #pragma unroll
  for (int it = 0; it < 8; ++it) wv[it] = Wr[it*64 + lane];
  float a0=0.f, a1=0.f, a2=0.f;
  #pragma unroll
  for (int it = 0; it < 8; ++it){
    int c = it*64 + lane;
    a0 += dot4(wv[it], shX[c]);
    a1 += dot4(wv[it], shX[512 + c]);
    a2 += dot4(wv[it], shX[1024 + c]);
  }
  a0 = wred(a0); a1 = wred(a1); a2 = wred(a2);
  if (lane == 0){
    float bb = bias[row];
    O[row] = a0 + bb; O[H3 + row] = a1 + bb; O[2*H3 + row] = a2 + bb;
  }
}

// GRU gate combine for the comm cell (h = hidden_state)
__global__ void k_gate_c(const float* __restrict__ gi, const float* __restrict__ gh,
                         const float* __restrict__ hprev,
                         float* __restrict__ hout_ws, float* __restrict__ dout){
  int id = blockIdx.x * blockDim.x + threadIdx.x;
  if (id >= 3*HU) return;
  int b = id >> 11, u = id & 2047;
  const float* gib = gi + b*H3;
  const float* ghb = gh + b*H3;
  float r = sigm(gib[u]      + ghb[u]);
  float z = sigm(gib[HU+u]   + ghb[HU+u]);
  float n = tanhf(gib[2*HU+u] + r*ghb[2*HU+u]);
  float h = hprev[id];
  float o = (1.f - z)*n + z*h;
  hout_ws[id] = o;
  dout[id] = o;
}

// --- big pass: stream Wih_f, Wih_r ONCE producing gi for BOTH steps; + q,k ---
// 512 threads = 8 rows per block.
// blocks [0,768): Wih_f ; [768,1536): Wih_r ; [1536,1600): Wq ; [1600,1664): Wk
// gi layout: [(t*3+b)*6144 + row]
__global__ __launch_bounds__(512) void k_ih(
    const float* __restrict__ Wf, const float* __restrict__ bf, float* __restrict__ giF,
    const float* __restrict__ Wr_, const float* __restrict__ br, float* __restrict__ giR,
    const float* __restrict__ Wq, float* __restrict__ q,
    const float* __restrict__ Wk, float* __restrict__ kk,
    const float* __restrict__ hout){
  __shared__ float4 shH[1536];
  int tid = threadIdx.x;
  const float4* H4 = (const float4*)hout;
  #pragma unroll
  for (int i = 0; i < 3; ++i) shH[tid + i*512] = H4[tid + i*512];
  __syncthreads();
  int blk = blockIdx.x;
  int wave = tid >> 6, lane = tid & 63;
  if (blk < 1536){
    int segr = (blk >= 768);
    const float* W    = segr ? Wr_ : Wf;
    const float* bias = segr ? br  : bf;
    float* gi         = segr ? giR : giF;
    int row = (segr ? blk - 768 : blk) * 8 + wave;
    const float4* Wrow = (const float4*)(W + (size_t)row * 4096);
    float s0=0.f,s1=0.f,s2=0.f,n0=0.f,n1=0.f,n2=0.f;
    float4 wv[8];
    #pragma unroll
    for (int it = 0; it < 8; ++it) wv[it] = Wrow[it*64 + lane];       // self half
    #pragma unroll
    for (int it = 0; it < 8; ++it){
      int c = it*64 + lane;
      s0 += dot4(wv[it], shH[c]); s1 += dot4(wv[it], shH[512+c]); s2 += dot4(wv[it], shH[1024+c]);
    }
    #pragma unroll
    for (int it = 0; it < 8; ++it) wv[it] = Wrow[512 + it*64 + lane]; // neighbor half
    #pragma unroll
    for (int it = 0; it < 8; ++it){
      int c = it*64 + lane;
      n0 += dot4(wv[it], shH[c]); n1 += dot4(wv[it], shH[512+c]); n2 += dot4(wv[it], shH[1024+c]);
    }
    s0=wred(s0); s1=wred(s1); s2=wred(s2);
    n0=wred(n0); n1=wred(n1); n2=wred(n2);
    if (lane == 0){
      float bb = bias[row];
      // IDX = [[1,2],[0,2],[0,1]]
      gi[0*H3 + row] = s0 + n1 + bb;  // t=0 b=0 (nbr 1)
      gi[1*H3 + row] = s1 + n0 + bb;  // t=0 b=1 (nbr 0)
      gi[2*H3 + row] = s2 + n0 + bb;  // t=0 b=2 (nbr 0)
      gi[3*H3 + row] = s0 + n2 + bb;  // t=1 b=0 (nbr 2)
      gi[4*H3 + row] = s1 + n2 + bb;  // t=1 b=1 (nbr 2)
      gi[5*H3 + row] = s2 + n1 + bb;  // t=1 b=2 (nbr 1)
    }
  } else {
    int segk = (blk >= 1600);
    const float* W = segk ? Wk : Wq;
    float* O       = segk ? kk : q;
    int row = (segk ? blk - 1600 : blk - 1536) * 8 + wave; // 0..511
    const float4* Wrow = (const float4*)(W + (size_t)row * 2048);
    float4 wv[8];
    #pragma unroll
    for (int it = 0; it < 8; ++it) wv[it] = Wrow[it*64 + lane];
    float a0=0.f, a1=0.f, a2=0.f;
    #pragma unroll
    for (int it = 0; it < 8; ++it){
      int c = it*64 + lane;
      a0 += dot4(wv[it], shH[c]); a1 += dot4(wv[it], shH[512+c]); a2 += dot4(wv[it], shH[1024+c]);
    }
    a0=wred(a0); a1=wred(a1); a2=wred(a2);
    if (lane == 0){ O[row] = a0; O[512 + row] = a1; O[1024 + row] = a2; }
  }
}

// step 0 of both scans: h=0 so gh == bhh
// forward consumes seq[0]  -> giF t=0 block (b*H3)
// reverse consumes seq[1]  -> giR t=1 block ((3+b)*H3)   [seq reversed!]
__global__ void k_gate0(const float* __restrict__ giF, const float* __restrict__ bhf,
                        float* __restrict__ hf1,
                        const float* __restrict__ giR, const float* __restrict__ bhr,
                        float* __restrict__ hr1){
  int id = blockIdx.x * blockDim.x + threadIdx.x;
  if (id >= 3*HU) return;
  int b = id >> 11, u = id & 2047;
  {
    const float* gib = giF + b*H3;                    // forward t=0 block
    float r = sigm(gib[u]      + bhf[u]);
    float z = sigm(gib[HU+u]   + bhf[HU+u]);
    float n = tanhf(gib[2*HU+u] + r*bhf[2*HU+u]);
    hf1[id] = (1.f - z)*n;
  }
  {
    const float* gib = giR + (3 + b)*H3;              // reverse t=1 block
    float r = sigm(gib[u]      + bhr[u]);
    float z = sigm(gib[HU+u]   + bhr[HU+u]);
    float n = tanhf(gib[2*HU+u] + r*bhr[2*HU+u]);
    hr1[id] = (1.f - z)*n;
  }
}

// step 1 of both scans
// forward consumes seq[1] -> giF t=1 block; reverse consumes seq[0] -> giR t=0 block
__global__ void k_gate1(const float* __restrict__ giF, const float* __restrict__ ghF,
                        const float* __restrict__ hf1, float* __restrict__ hf2,
                        const float* __restrict__ giR, const float* __restrict__ ghR,
                        const float* __restrict__ hr1, float* __restrict__ hr2){
  int id = blockIdx.x * blockDim.x + threadIdx.x;
  if (id >= 3*HU) return;
  int b = id >> 11, u = id & 2047;
  {
    const float* gib = giF + (3 + b)*H3;              // forward t=1 block
    const float* ghb = ghF + b*H3;
    float r = sigm(gib[u]      + ghb[u]);
    float z = sigm(gib[HU+u]   + ghb[HU+u]);
    float n = tanhf(gib[2*HU+u] + r*ghb[2*HU+u]);
    hf2[id] = (1.f - z)*n + z*hf1[id];
  }
  {
    const float* gib = giR + b*H3;                    // reverse t=0 block
    const float* ghb = ghR + b*H3;
    float r = sigm(gib[u]      + ghb[u]);
    float z = sigm(gib[HU+u]   + ghb[HU+u]);
    float n = tanhf(gib[2*HU+u] + r*ghb[2*HU+u]);
    hr2[id] = (1.f - z)*n + z*hr1[id];
  }
}

// final small kernel: logits, gumbel softmax, q.k attention, xx, flag
__global__ __launch_bounds__(256) void k_final(
    const float* __restrict__ hf1, const float* __restrict__ hf2,
    const float* __restrict__ hr1, const float* __restrict__ hr2,
    const float* __restrict__ q, const float* __restrict__ kk,
    const float* __restrict__ Whard, const float* __restrict__ bhard,
    const float* __restrict__ gumbel, const float* __restrict__ obs,
    float* __restrict__ dout){
  __shared__ float slog[12];
  __shared__ float ssc[6];
  int tid = threadIdx.x;
  int wave = tid >> 6, lane = tid & 63;
  // 12 logit dots: d = row*2 + c ; row = i*2 + t ; h_hard row = [F | R]
  // h_hard[t=0] = [hf1 | outs_r[1]=hr2] ; h_hard[t=1] = [hf2 | outs_r[0]=hr1]
  #pragma unroll
  for (int s = 0; s < 3; ++s){
    int d = wave*3 + s;
    int rowi = d >> 1, c = d & 1;
    int i = rowi >> 1, t = rowi & 1;
    const float* F = (t ? hf2 : hf1) + i*HU;
    const float* R = (t ? hr1 : hr2) + i*HU;
    const float* w0 = Whard + c*4096;
    float acc = 0.f;
    for (int j = lane; j < HU; j += 64) acc += w0[j]*F[j] + w0[HU + j]*R[j];
    acc = wred(acc);
    if (lane == 0) slog[d] = acc + bhard[c];
  }
  // 6 attention score dots
  {
    const int nbr[6] = {1,2, 0,2, 0,1};   // IDX flattened, index = i*2+j
    for (int d = wave; d < 6; d += 4){
      int i = d >> 1;
      const float* qv = q + i*512;
      const float* kv = kk + nbr[d]*512;
      float acc = 0.f;
      for (int a = lane; a < 512; a += 64) acc += qv[a]*kv[a];
      acc = wred(acc);
      if (lane == 0) ssc[d] = acc * 0.04419417382415922f;  // 1/sqrt(512)
    }
  }
  __syncthreads();
  if (tid == 0){
    float y1[6];
    #pragma unroll
    for (int rr = 0; rr < 6; ++rr){
      float a0 = (slog[rr*2+0] + gumbel[rr*2+0]) * 100.0f;  // /TAU
      float a1 = (slog[rr*2+1] + gumbel[rr*2+1]) * 100.0f;
      y1[rr] = 1.0f/(1.0f + expf(a0 - a1));
    }
    #pragma unroll
    for (int i = 0; i < 3; ++i){
      float s0 = ssc[i*2], s1 = ssc[i*2+1];
      float m = fmaxf(s0, s1);
      float e0 = expf(s0 - m), e1 = expf(s1 - m);
      float inv = 1.0f/(e0 + e1);
      dout[6144 + i*2 + 0] = e0*inv * y1[i*2 + 0];
      dout[6144 + i*2 + 1] = e1*inv * y1[i*2 + 1];
    }
    // flag from obs
    const int idx[3][2] = {{1,2},{0,2},{0,1}};
    int temp[3][2];
    #pragma unroll
    for (int i = 0; i < 3; ++i){
      float res[2];
      #pragma unroll
      for (int j = 0; j < 2; ++j){
        float s = 0.f;
        for (int k2 = 0; k2 < 42; ++k2){
          float d2 = obs[i*42 + k2] - obs[idx[i][j]*42 + k2];
          s += d2*d2;
        }
        res[j] = s;
      }
      int jloc = (res[1] > res[0]) ? 1 : 0;   // argmax, first-on-tie
      float maxv = res[jloc];
      int jadj = (maxv != 0.0f && jloc >= i) ? jloc + 1 : jloc;
      int lo = min(i, jadj), hi = max(i, jadj);
      temp[i][0] = lo; temp[i][1] = hi;
    }
    bool eq01 = temp[0][0]==temp[1][0] && temp[0][1]==temp[1][1];
    bool eq02 = temp[0][0]==temp[2][0] && temp[0][1]==temp[2][1];
    bool eq12 = temp[1][0]==temp[2][0] && temp[1][1]==temp[2][1];
    int f0, f1;
    if (eq12){ f0 = temp[1][0]; f1 = temp[1][1]; }
    else if (eq01 || eq02){ f0 = temp[0][0]; f1 = temp[0][1]; }
    else { f0 = -1; f1 = -1; }
    dout[6150] = (float)f0;
    dout[6151] = (float)f1;
  }
}

extern "C" void kernel_launch(void* const* d_in, const int* in_sizes, int n_in,
                              void* d_out, int out_size, void* d_ws, size_t ws_size,
                              hipStream_t stream) {
  const float* obs    = (const float*)d_in[0];
  const float* hidden = (const float*)d_in[1];
  const float* gumbel = (const float*)d_in[2];
  const float* W_enc  = (const float*)d_in[3];
  const float* b_enc  = (const float*)d_in[4];
  const float* Wih_c  = (const float*)d_in[5];
  const float* Whh_c  = (const float*)d_in[6];
  const float* bih_c  = (const float*)d_in[7];
  const float* bhh_c  = (const float*)d_in[8];
  const float* Wih_f  = (const float*)d_in[9];
  const float* Whh_f  = (const float*)d_in[10];
  const float* bih_f  = (const float*)d_in[11];
  const float* bhh_f  = (const float*)d_in[12];
  const float* Wih_r  = (const float*)d_in[13];
  const float* Whh_r  = (const float*)d_in[14];
  const float* bih_r  = (const float*)d_in[15];
  const float* bhh_r  = (const float*)d_in[16];
  const float* W_hard = (const float*)d_in[17];
  const float* b_hard = (const float*)d_in[18];
  const float* Wq     = (const float*)d_in[19];
  const float* Wk     = (const float*)d_in[20];

  float* out = (float*)d_out;
  float* ws  = (float*)d_ws;
  float* x    = ws;            // 6144
  float* hout = ws + 6144;     // 6144
  float* gic  = ws + 12288;    // 18432
  float* ghc  = ws + 30720;    // 18432
  float* gif  = ws + 49152;    // 36864  [(t*3+b)*6144 + r]
  float* gir  = ws + 86016;    // 36864
  float* ghf  = ws + 122880;   // 18432
  float* ghr  = ws + 141312;   // 18432
  float* hf1  = ws + 159744;   // 6144
  float* hr1  = ws + 165888;   // 6144
  float* hf2  = ws + 172032;   // 6144
  float* hr2  = ws + 178176;   // 6144
  float* q    = ws + 184320;   // 1536
  float* kk   = ws + 185856;   // 1536

  k_enc<<<8, 256, 0, stream>>>(obs, W_enc, b_enc, x);
  k_gemv2k<<<1536, 512, 0, stream>>>(Wih_c, x, bih_c, gic, Whh_c, hidden, bhh_c, ghc);
  k_gate_c<<<24, 256, 0, stream>>>(gic, ghc, hidden, hout, out);
  k_ih<<<1664, 512, 0, stream>>>(Wih_f, bih_f, gif, Wih_r, bih_r, gir, Wq, q, Wk, kk, hout);
  k_gate0<<<24, 256, 0, stream>>>(gif, bhh_f, hf1, gir, bhh_r, hr1);
  k_gemv2k<<<1536, 512, 0, stream>>>(Whh_f, hf1, bhh_f, ghf, Whh_r, hr1, bhh_r, ghr);
  k_gate1<<<24, 256, 0, stream>>>(gif, ghf, hf1, hf2, gir, ghr, hr1, hr2);
  k_final<<<1, 256, 0, stream>>>(hf1, hf2, hr1, hr2, q, kk, W_hard, b_hard, gumbel, obs, out);
}